// Round 1
// baseline (420.335 us; speedup 1.0000x reference)
//
#include <hip/hip_runtime.h>
#include <hip/hip_bf16.h>
#include <stdint.h>

typedef __attribute__((ext_vector_type(8))) short bf16x8;
typedef __attribute__((ext_vector_type(4))) float f32x4;

#define GLOAD16(gptr, lptr)                                              \
  __builtin_amdgcn_global_load_lds(                                      \
      (const __attribute__((address_space(1))) void*)(gptr),             \
      (__attribute__((address_space(3))) void*)(lptr), 16, 0, 0)

// ---------------------------------------------------------------- cvt f32->bf16
__global__ __launch_bounds__(256)
void cvt_kernel(const float* __restrict__ in, __hip_bfloat16* __restrict__ out, int n)
{
  long i = ((long)blockIdx.x * 256 + threadIdx.x) * 8;
  if (i + 8 > n) return;
  float4 a = *(const float4*)(in + i);
  float4 b = *(const float4*)(in + i + 4);
  union { __hip_bfloat16 h[8]; uint4 q; } r;
  r.h[0] = __float2bfloat16(a.x); r.h[1] = __float2bfloat16(a.y);
  r.h[2] = __float2bfloat16(a.z); r.h[3] = __float2bfloat16(a.w);
  r.h[4] = __float2bfloat16(b.x); r.h[5] = __float2bfloat16(b.y);
  r.h[6] = __float2bfloat16(b.z); r.h[7] = __float2bfloat16(b.w);
  *(uint4*)(out + i) = r.q;
}

// ------------------------------------------- weight transpose+convert: [K][N]f32 -> [N][K]bf16
__global__ __launch_bounds__(256)
void wtrans_kernel(const float* __restrict__ in, __hip_bfloat16* __restrict__ out)
{
  __shared__ float t[64][65];
  const int tx = threadIdx.x & 15, ty = threadIdx.x >> 4;
  const int bx = blockIdx.x, by = blockIdx.y;
  for (int i = 0; i < 4; ++i)
    for (int j = 0; j < 4; ++j)
      t[ty*4+i][tx*4+j] = in[(long)(by*64 + ty*4+i)*1024 + bx*64 + tx*4 + j];
  __syncthreads();
  for (int i = 0; i < 4; ++i)
    for (int j = 0; j < 4; ++j)
      out[(long)(bx*64 + ty*4+i)*1024 + by*64 + tx*4 + j] =
          __float2bfloat16(t[tx*4+j][ty*4+i]);
}

// ------------------------------------------- V transpose: [bh][s][d] -> [bh][d][s] (bf16)
__global__ __launch_bounds__(256)
void vtrans_kernel(const __hip_bfloat16* __restrict__ in, __hip_bfloat16* __restrict__ out)
{
  __shared__ __hip_bfloat16 t[64][72];
  const int tx = threadIdx.x & 15, ty = threadIdx.x >> 4;
  const int sb = blockIdx.x, bh = blockIdx.y;
  const __hip_bfloat16* inp = in + (long)bh * 2048 * 64;
  __hip_bfloat16* outp = out + (long)bh * 64 * 2048;
  for (int i = 0; i < 4; ++i)
    for (int j = 0; j < 4; ++j)
      t[ty*4+i][tx*4+j] = inp[(long)(sb*64 + ty*4+i)*64 + tx*4 + j];
  __syncthreads();
  for (int i = 0; i < 4; ++i)
    for (int j = 0; j < 4; ++j)
      outp[(long)(ty*4+i)*2048 + sb*64 + tx*4 + j] = t[tx*4+j][ty*4+i];
}

// ---------------------------------------------------------------- 128x128 bf16 GEMM, B^T input
// EPI 0: bf16 out permuted to [b][h][s][d], scaled
// EPI 2: fp32 out row-major + bias[col] + resid[row][col]
template<int EPI>
__global__ __launch_bounds__(256)
void gemm_bt(const __hip_bfloat16* __restrict__ A,   // [M][K]
             const __hip_bfloat16* __restrict__ Bt,  // [N][K]
             void* __restrict__ out,
             const float* __restrict__ bias,
             const float* __restrict__ resid,
             int M, int N, int K, float scale)
{
  __shared__ __hip_bfloat16 As[128*32];
  __shared__ __hip_bfloat16 Bs[128*32];
  const int tid = threadIdx.x;
  const int wid = tid >> 6;
  const int lane = tid & 63;
  const int lr = lane & 15, lg = lane >> 4;
  const int bm = blockIdx.y, bn = blockIdx.x;
  const int wm = wid >> 1, wn = wid & 1;

  f32x4 acc[4][4] = {};

  const int srow = tid >> 2;          // 0..63
  const int scol = (tid & 3) * 8;
  const __hip_bfloat16* Ag = A  + (long)(bm*128 + srow)*K + scol;
  const __hip_bfloat16* Bg = Bt + (long)(bn*128 + srow)*K + scol;
  __hip_bfloat16* AsW = &As[wid*512];
  __hip_bfloat16* BsW = &Bs[wid*512];

  for (int k0 = 0; k0 < K; k0 += 32) {
    GLOAD16(Ag + k0,          AsW);
    GLOAD16(Ag + 64*K + k0,   AsW + 2048);
    GLOAD16(Bg + k0,          BsW);
    GLOAD16(Bg + 64*K + k0,   BsW + 2048);
    __syncthreads();
    bf16x8 a[4], b[4];
    for (int m = 0; m < 4; ++m)
      a[m] = *(const bf16x8*)&As[(wm*64 + m*16 + lr)*32 + lg*8];
    for (int n = 0; n < 4; ++n)
      b[n] = *(const bf16x8*)&Bs[(wn*64 + n*16 + lr)*32 + lg*8];
    for (int m = 0; m < 4; ++m)
      for (int n = 0; n < 4; ++n)
        acc[m][n] = __builtin_amdgcn_mfma_f32_16x16x32_bf16(a[m], b[n], acc[m][n], 0, 0, 0);
    __syncthreads();
  }

  for (int m = 0; m < 4; ++m) {
    const int grow0 = bm*128 + wm*64 + m*16 + lg*4;
    for (int n = 0; n < 4; ++n) {
      const int gcol = bn*128 + wn*64 + n*16 + lr;
      for (int j = 0; j < 4; ++j) {
        const int grow = grow0 + j;
        float val = acc[m][n][j] * scale;
        if (EPI == 0) {
          const int b_ = grow >> 11, s = grow & 2047;
          const int h = gcol >> 6, d = gcol & 63;
          ((__hip_bfloat16*)out)[((long)(b_*16 + h)*2048 + s)*64 + d] = __float2bfloat16(val);
        } else {
          ((float*)out)[(long)grow*N + gcol] =
              val + bias[gcol] + resid[(long)grow*N + gcol];
        }
      }
    }
  }
}

// ---------------------------------------------------------------- attention
// Qh,Kh: [bh][2048][64] bf16 (Q pre-scaled 1/32); Vt: [bh][64][2048] bf16
// attn_out: [bh][2048][2048] f32; O: [4096][1024] bf16 ([b*2048+s][h*64+d])
__global__ __launch_bounds__(256)
void attn_kernel(const __hip_bfloat16* __restrict__ Qh,
                 const __hip_bfloat16* __restrict__ Kh,
                 const __hip_bfloat16* __restrict__ Vt,
                 float* __restrict__ attn_out,
                 __hip_bfloat16* __restrict__ O)
{
  __shared__ __hip_bfloat16 Qs[64*64];
  __shared__ __hip_bfloat16 Ks[128*64];
  __shared__ __hip_bfloat16 Vs[64*128];   // [d][kv]
  __shared__ __hip_bfloat16 Ps[64*128];
  __shared__ float red[4][64];
  __shared__ float invl[64];

  const int tid = threadIdx.x, wid = tid >> 6, lane = tid & 63;
  const int lr = lane & 15, lg = lane >> 4;
  const int qb = blockIdx.x, bh = blockIdx.y;

  const __hip_bfloat16* Qg    = Qh + ((long)bh*2048 + qb*64)*64;
  const __hip_bfloat16* Kbase = Kh + (long)bh*2048*64;
  const __hip_bfloat16* Vbase = Vt + (long)bh*64*2048;

  GLOAD16(Qg + tid*8,        &Qs[wid*512]);
  GLOAD16(Qg + 2048 + tid*8, &Qs[2048 + wid*512]);
  __syncthreads();

  bf16x8 aq[4][2];
  for (int m = 0; m < 4; ++m)
    for (int kk = 0; kk < 2; ++kk)
      aq[m][kk] = *(const bf16x8*)&Qs[(m*16 + lr)*64 + kk*32 + lg*8];

  float rs[4][4] = {};

  // ---- pass 1: row sums of exp(S)
  for (int kt = 0; kt < 16; ++kt) {
    const __hip_bfloat16* Kg = Kbase + kt*8192;
    for (int r = 0; r < 4; ++r)
      GLOAD16(Kg + r*2048 + tid*8, &Ks[r*2048 + wid*512]);
    __syncthreads();
    bf16x8 bk[2][2];
    for (int n = 0; n < 2; ++n)
      for (int kk = 0; kk < 2; ++kk)
        bk[n][kk] = *(const bf16x8*)&Ks[(wid*32 + n*16 + lr)*64 + kk*32 + lg*8];
    f32x4 s[4][2] = {};
    for (int m = 0; m < 4; ++m)
      for (int n = 0; n < 2; ++n)
        for (int kk = 0; kk < 2; ++kk)
          s[m][n] = __builtin_amdgcn_mfma_f32_16x16x32_bf16(aq[m][kk], bk[n][kk], s[m][n], 0, 0, 0);
    for (int m = 0; m < 4; ++m)
      for (int j = 0; j < 4; ++j) {
        float e = __expf(s[m][0][j]) + __expf(s[m][1][j]);
        for (int o = 1; o < 16; o <<= 1) e += __shfl_xor(e, o, 64);
        rs[m][j] += e;
      }
    __syncthreads();
  }

  if (lr == 0)
    for (int m = 0; m < 4; ++m)
      for (int j = 0; j < 4; ++j)
        red[wid][m*16 + lg*4 + j] = rs[m][j];
  __syncthreads();
  if (tid < 64)
    invl[tid] = 1.0f / (red[0][tid] + red[1][tid] + red[2][tid] + red[3][tid]);
  __syncthreads();

  float iv[4][4];
  for (int m = 0; m < 4; ++m)
    for (int j = 0; j < 4; ++j)
      iv[m][j] = invl[m*16 + lg*4 + j];

  // ---- pass 2: write attn, accumulate O = P*V
  f32x4 acc_o[4] = {};
  float* attn_row = attn_out + ((long)bh*2048 + qb*64)*2048;

  for (int kt = 0; kt < 16; ++kt) {
    const __hip_bfloat16* Kg = Kbase + kt*8192;
    const __hip_bfloat16* Vg = Vbase + kt*128;
    for (int r = 0; r < 4; ++r)
      GLOAD16(Kg + r*2048 + tid*8, &Ks[r*2048 + wid*512]);
    for (int r = 0; r < 4; ++r)
      GLOAD16(Vg + (long)(r*16 + (tid >> 4))*2048 + (tid & 15)*8, &Vs[r*2048 + wid*512]);
    __syncthreads();

    bf16x8 bk[2][2];
    for (int n = 0; n < 2; ++n)
      for (int kk = 0; kk < 2; ++kk)
        bk[n][kk] = *(const bf16x8*)&Ks[(wid*32 + n*16 + lr)*64 + kk*32 + lg*8];
    f32x4 s[4][2] = {};
    for (int m = 0; m < 4; ++m)
      for (int n = 0; n < 2; ++n)
        for (int kk = 0; kk < 2; ++kk)
          s[m][n] = __builtin_amdgcn_mfma_f32_16x16x32_bf16(aq[m][kk], bk[n][kk], s[m][n], 0, 0, 0);

    for (int m = 0; m < 4; ++m)
      for (int n = 0; n < 2; ++n) {
        const int col = wid*32 + n*16 + lr;
        for (int j = 0; j < 4; ++j) {
          const float p = __expf(s[m][n][j]) * iv[m][j];
          const int row = m*16 + lg*4 + j;
          attn_row[(long)row*2048 + kt*128 + col] = p;
          Ps[row*128 + col] = __float2bfloat16(p);
        }
      }
    __syncthreads();

    bf16x8 vb[4];
    for (int kk2 = 0; kk2 < 4; ++kk2)
      vb[kk2] = *(const bf16x8*)&Vs[(wid*16 + lr)*128 + kk2*32 + lg*8];
    for (int m = 0; m < 4; ++m)
      for (int kk2 = 0; kk2 < 4; ++kk2) {
        bf16x8 pa = *(const bf16x8*)&Ps[(m*16 + lr)*128 + kk2*32 + lg*8];
        acc_o[m] = __builtin_amdgcn_mfma_f32_16x16x32_bf16(pa, vb[kk2], acc_o[m], 0, 0, 0);
      }
    __syncthreads();
  }

  const int b_ = bh >> 4, h = bh & 15;
  for (int m = 0; m < 4; ++m)
    for (int j = 0; j < 4; ++j) {
      const long grow = (long)b_*2048 + qb*64 + m*16 + lg*4 + j;
      O[grow*1024 + h*64 + wid*16 + lr] = __float2bfloat16(acc_o[m][j]);
    }
}

// ---------------------------------------------------------------- layernorm
__global__ __launch_bounds__(256)
void ln_kernel(const float* __restrict__ xin, const float* __restrict__ gam,
               const float* __restrict__ bet, float* __restrict__ xout)
{
  const int row = blockIdx.x;
  const int tid = threadIdx.x;
  const float* xr = xin + (long)row*1024;
  float4 v = *(const float4*)(xr + tid*4);
  float s  = v.x + v.y + v.z + v.w;
  float ss = v.x*v.x + v.y*v.y + v.z*v.z + v.w*v.w;
  for (int o = 1; o < 64; o <<= 1) {
    s  += __shfl_xor(s, o, 64);
    ss += __shfl_xor(ss, o, 64);
  }
  __shared__ float rsh[4], rssh[4];
  const int wid = tid >> 6, lane = tid & 63;
  if (lane == 0) { rsh[wid] = s; rssh[wid] = ss; }
  __syncthreads();
  s  = rsh[0] + rsh[1] + rsh[2] + rsh[3];
  ss = rssh[0] + rssh[1] + rssh[2] + rssh[3];
  const float mean = s * (1.0f/1024.0f);
  const float var  = ss * (1.0f/1024.0f) - mean*mean;
  const float rstd = rsqrtf(var + 1e-5f);
  float4 g4 = *(const float4*)(gam + tid*4);
  float4 b4 = *(const float4*)(bet + tid*4);
  float4 o4;
  o4.x = (v.x - mean)*rstd*g4.x + b4.x;
  o4.y = (v.y - mean)*rstd*g4.y + b4.y;
  o4.z = (v.z - mean)*rstd*g4.z + b4.z;
  o4.w = (v.w - mean)*rstd*g4.w + b4.w;
  *(float4*)(xout + (long)row*1024 + tid*4) = o4;
}

// ---------------------------------------------------------------- launch
extern "C" void kernel_launch(void* const* d_in, const int* in_sizes, int n_in,
                              void* d_out, int out_size, void* d_ws, size_t ws_size,
                              hipStream_t stream)
{
  (void)in_sizes; (void)n_in; (void)out_size; (void)ws_size;
  const float* q    = (const float*)d_in[0];
  const float* k    = (const float*)d_in[1];
  const float* v    = (const float*)d_in[2];
  const float* w_q  = (const float*)d_in[3];
  const float* w_k  = (const float*)d_in[4];
  const float* w_v  = (const float*)d_in[5];
  const float* w_fc = (const float*)d_in[6];
  const float* b_fc = (const float*)d_in[7];
  const float* ln_g = (const float*)d_in[8];
  const float* ln_b = (const float*)d_in[9];

  const long MB = 1024*1024;
  char* ws = (char*)d_ws;
  __hip_bfloat16* q_bf  = (__hip_bfloat16*)(ws);
  __hip_bfloat16* k_bf  = (__hip_bfloat16*)(ws +  8*MB);
  __hip_bfloat16* v_bf  = (__hip_bfloat16*)(ws + 16*MB);
  __hip_bfloat16* wq_t  = (__hip_bfloat16*)(ws + 24*MB);
  __hip_bfloat16* wk_t  = (__hip_bfloat16*)(ws + 26*MB);
  __hip_bfloat16* wv_t  = (__hip_bfloat16*)(ws + 28*MB);
  __hip_bfloat16* wfc_t = (__hip_bfloat16*)(ws + 30*MB);
  __hip_bfloat16* Qh    = (__hip_bfloat16*)(ws + 32*MB);
  __hip_bfloat16* Kh    = (__hip_bfloat16*)(ws + 40*MB);
  __hip_bfloat16* Vh    = (__hip_bfloat16*)(ws + 48*MB);
  __hip_bfloat16* Vht   = (__hip_bfloat16*)(ws + 56*MB);
  __hip_bfloat16* Obuf  = (__hip_bfloat16*)(ws + 64*MB);
  float*          xbuf  = (float*)(ws + 72*MB);

  float* x_out    = (float*)d_out;
  float* attn_out = x_out + 4194304L;

  const int NQ = 4096*1024;
  cvt_kernel<<<NQ/2048, 256, 0, stream>>>(q, q_bf, NQ);
  cvt_kernel<<<NQ/2048, 256, 0, stream>>>(k, k_bf, NQ);
  cvt_kernel<<<NQ/2048, 256, 0, stream>>>(v, v_bf, NQ);

  dim3 wtg(16, 16);
  wtrans_kernel<<<wtg, 256, 0, stream>>>(w_q,  wq_t);
  wtrans_kernel<<<wtg, 256, 0, stream>>>(w_k,  wk_t);
  wtrans_kernel<<<wtg, 256, 0, stream>>>(w_v,  wv_t);
  wtrans_kernel<<<wtg, 256, 0, stream>>>(w_fc, wfc_t);

  dim3 gg(8, 32);
  gemm_bt<0><<<gg, 256, 0, stream>>>(q_bf, wq_t, Qh, nullptr, nullptr, 4096, 1024, 1024, 0.03125f);
  gemm_bt<0><<<gg, 256, 0, stream>>>(k_bf, wk_t, Kh, nullptr, nullptr, 4096, 1024, 1024, 1.0f);
  gemm_bt<0><<<gg, 256, 0, stream>>>(v_bf, wv_t, Vh, nullptr, nullptr, 4096, 1024, 1024, 1.0f);

  vtrans_kernel<<<dim3(32, 32), 256, 0, stream>>>(Vh, Vht);

  attn_kernel<<<dim3(32, 32), 256, 0, stream>>>(Qh, Kh, Vht, attn_out, Obuf);

  gemm_bt<2><<<gg, 256, 0, stream>>>(Obuf, wfc_t, xbuf, b_fc, q, 4096, 1024, 1024, 1.0f);

  ln_kernel<<<4096, 256, 0, stream>>>(xbuf, ln_g, ln_b, x_out);
}

// Round 2
// 308.976 us; speedup vs baseline: 1.3604x; 1.3604x over previous
//
#include <hip/hip_runtime.h>
#include <hip/hip_bf16.h>
#include <stdint.h>

typedef __attribute__((ext_vector_type(8))) short bf16x8;
typedef __attribute__((ext_vector_type(4))) float f32x4;

#define GLOAD16(gptr, lptr)                                              \
  __builtin_amdgcn_global_load_lds(                                      \
      (const __attribute__((address_space(1))) void*)(gptr),             \
      (__attribute__((address_space(3))) void*)(lptr), 16, 0, 0)

// ---------------------------------------------------------------- cvt f32->bf16 (q,k,v fused)
__global__ __launch_bounds__(256)
void cvt_kernel(const float* __restrict__ in0, const float* __restrict__ in1,
                const float* __restrict__ in2, __hip_bfloat16* __restrict__ out0,
                __hip_bfloat16* __restrict__ out1, __hip_bfloat16* __restrict__ out2,
                int n)
{
  const int z = blockIdx.y;
  const float* in = z == 0 ? in0 : z == 1 ? in1 : in2;
  __hip_bfloat16* out = z == 0 ? out0 : z == 1 ? out1 : out2;
  long i = ((long)blockIdx.x * 256 + threadIdx.x) * 8;
  if (i + 8 > n) return;
  float4 a = *(const float4*)(in + i);
  float4 b = *(const float4*)(in + i + 4);
  union { __hip_bfloat16 h[8]; uint4 q; } r;
  r.h[0] = __float2bfloat16(a.x); r.h[1] = __float2bfloat16(a.y);
  r.h[2] = __float2bfloat16(a.z); r.h[3] = __float2bfloat16(a.w);
  r.h[4] = __float2bfloat16(b.x); r.h[5] = __float2bfloat16(b.y);
  r.h[6] = __float2bfloat16(b.z); r.h[7] = __float2bfloat16(b.w);
  *(uint4*)(out + i) = r.q;
}

// ------------------------------------------- weight transpose+convert: [K][N]f32 -> [N][K]bf16 (4 fused)
__global__ __launch_bounds__(256)
void wtrans_kernel(const float* __restrict__ w0, const float* __restrict__ w1,
                   const float* __restrict__ w2, const float* __restrict__ w3,
                   __hip_bfloat16* __restrict__ o0, __hip_bfloat16* __restrict__ o1,
                   __hip_bfloat16* __restrict__ o2, __hip_bfloat16* __restrict__ o3)
{
  const int z = blockIdx.z;
  const float* in = z == 0 ? w0 : z == 1 ? w1 : z == 2 ? w2 : w3;
  __hip_bfloat16* out = z == 0 ? o0 : z == 1 ? o1 : z == 2 ? o2 : o3;
  __shared__ float t[64][65];
  const int tx = threadIdx.x & 15, ty = threadIdx.x >> 4;
  const int bx = blockIdx.x, by = blockIdx.y;
  for (int i = 0; i < 4; ++i)
    for (int j = 0; j < 4; ++j)
      t[ty*4+i][tx*4+j] = in[(long)(by*64 + ty*4+i)*1024 + bx*64 + tx*4 + j];
  __syncthreads();
  for (int i = 0; i < 4; ++i)
    for (int j = 0; j < 4; ++j)
      out[(long)(bx*64 + ty*4+i)*1024 + by*64 + tx*4 + j] =
          __float2bfloat16(t[tx*4+j][ty*4+i]);
}

// ------------------------------------------- V transpose: [bh][s][d] -> [bh][d][s] (bf16)
__global__ __launch_bounds__(256)
void vtrans_kernel(const __hip_bfloat16* __restrict__ in, __hip_bfloat16* __restrict__ out)
{
  __shared__ __hip_bfloat16 t[64][72];
  const int tx = threadIdx.x & 15, ty = threadIdx.x >> 4;
  const int sb = blockIdx.x, bh = blockIdx.y;
  const __hip_bfloat16* inp = in + (long)bh * 2048 * 64;
  __hip_bfloat16* outp = out + (long)bh * 64 * 2048;
  for (int i = 0; i < 4; ++i)
    for (int j = 0; j < 4; ++j)
      t[ty*4+i][tx*4+j] = inp[(long)(sb*64 + ty*4+i)*64 + tx*4 + j];
  __syncthreads();
  for (int i = 0; i < 4; ++i)
    for (int j = 0; j < 4; ++j)
      outp[(long)(ty*4+i)*2048 + sb*64 + tx*4 + j] = t[tx*4+j][ty*4+i];
}

// ---------------------------------------------------------------- 128x128 bf16 GEMM, B^T input
// EPI 0: fused QKV projections (blockIdx.z selects src/weight), bf16 out [b][h][s][d]
// EPI 2: fp32 out row-major + bias[col] + resid[row][col]
template<int EPI>
__global__ __launch_bounds__(256)
void gemm_bt(const __hip_bfloat16* __restrict__ A0,
             const __hip_bfloat16* __restrict__ A1,
             const __hip_bfloat16* __restrict__ A2,
             const __hip_bfloat16* __restrict__ B0,
             const __hip_bfloat16* __restrict__ B1,
             const __hip_bfloat16* __restrict__ B2,
             void* __restrict__ out,
             const float* __restrict__ bias,
             const float* __restrict__ resid,
             int M, int N, int K)
{
  const int z = (EPI == 0) ? blockIdx.z : 0;
  const __hip_bfloat16* A  = z == 0 ? A0 : z == 1 ? A1 : A2;
  const __hip_bfloat16* Bt = z == 0 ? B0 : z == 1 ? B1 : B2;
  const float scale = (EPI == 0 && z == 0) ? 0.03125f : 1.0f;

  __shared__ __hip_bfloat16 As[128*32];
  __shared__ __hip_bfloat16 Bs[128*32];
  const int tid = threadIdx.x;
  const int wid = tid >> 6;
  const int lane = tid & 63;
  const int lr = lane & 15, lg = lane >> 4;
  const int bm = blockIdx.y, bn = blockIdx.x;
  const int wm = wid >> 1, wn = wid & 1;

  f32x4 acc[4][4] = {};

  const int srow = tid >> 2;          // 0..63
  const int scol = (tid & 3) * 8;
  const __hip_bfloat16* Ag = A  + (long)(bm*128 + srow)*K + scol;
  const __hip_bfloat16* Bg = Bt + (long)(bn*128 + srow)*K + scol;
  __hip_bfloat16* AsW = &As[wid*512];
  __hip_bfloat16* BsW = &Bs[wid*512];

  for (int k0 = 0; k0 < K; k0 += 32) {
    GLOAD16(Ag + k0,          AsW);
    GLOAD16(Ag + 64*K + k0,   AsW + 2048);
    GLOAD16(Bg + k0,          BsW);
    GLOAD16(Bg + 64*K + k0,   BsW + 2048);
    __syncthreads();
    bf16x8 a[4], b[4];
    for (int m = 0; m < 4; ++m)
      a[m] = *(const bf16x8*)&As[(wm*64 + m*16 + lr)*32 + lg*8];
    for (int n = 0; n < 4; ++n)
      b[n] = *(const bf16x8*)&Bs[(wn*64 + n*16 + lr)*32 + lg*8];
    for (int m = 0; m < 4; ++m)
      for (int n = 0; n < 4; ++n)
        acc[m][n] = __builtin_amdgcn_mfma_f32_16x16x32_bf16(a[m], b[n], acc[m][n], 0, 0, 0);
    __syncthreads();
  }

  for (int m = 0; m < 4; ++m) {
    const int grow0 = bm*128 + wm*64 + m*16 + lg*4;
    for (int n = 0; n < 4; ++n) {
      const int gcol = bn*128 + wn*64 + n*16 + lr;
      for (int j = 0; j < 4; ++j) {
        const int grow = grow0 + j;
        float val = acc[m][n][j] * scale;
        if (EPI == 0) {
          const int b_ = grow >> 11, s = grow & 2047;
          const int h = gcol >> 6, d = gcol & 63;
          ((__hip_bfloat16*)out)[(long)z*4194304 +
              ((long)(b_*16 + h)*2048 + s)*64 + d] = __float2bfloat16(val);
        } else {
          ((float*)out)[(long)grow*N + gcol] =
              val + bias[gcol] + resid[(long)grow*N + gcol];
        }
      }
    }
  }
}

// ---------------------------------------------------------------- attention
// Qh,Kh: [bh][2048][64] bf16 (Q pre-scaled 1/32); Vt: [bh][64][2048] bf16
// attn_out: [bh][2048][2048] f32; O: [4096][1024] bf16 ([b*2048+s][h*64+d])
// LDS layouts XOR-swizzled: K/Q rows 128B, slot^=(row&7); V/P rows 256B, slot^=(row&15).
// global_load_lds dest stays linear; the swizzle is realized by pre-swizzling the
// per-lane GLOBAL source address (m173 pattern).
__global__ __launch_bounds__(256)
void attn_kernel(const __hip_bfloat16* __restrict__ Qh,
                 const __hip_bfloat16* __restrict__ Kh,
                 const __hip_bfloat16* __restrict__ Vt,
                 float* __restrict__ attn_out,
                 __hip_bfloat16* __restrict__ O)
{
  __shared__ __hip_bfloat16 Qs[64*64];
  __shared__ __hip_bfloat16 Ks[128*64];
  __shared__ __hip_bfloat16 Vs[64*128];   // [d][kv]
  __shared__ __hip_bfloat16 Ps[64*128];
  __shared__ float red[4][64];
  __shared__ float invl[64];

  const int tid = threadIdx.x, wid = tid >> 6, lane = tid & 63;
  const int lr = lane & 15, lg = lane >> 4;
  const int qb = blockIdx.x, bh = blockIdx.y;

  const __hip_bfloat16* Qg    = Qh + ((long)bh*2048 + qb*64)*64;
  const __hip_bfloat16* Kbase = Kh + (long)bh*2048*64;
  const __hip_bfloat16* Vbase = Vt + (long)bh*64*2048;

  // --- Q staging, swizzled source: dest row = r*32 + wid*8 + (lane>>3), slot = lane&7
  for (int r = 0; r < 2; ++r) {
    const int row = r*32 + wid*8 + (lane >> 3);
    const int sl  = (lane & 7) ^ (row & 7);
    GLOAD16(Qg + row*64 + sl*8, &Qs[r*2048 + wid*512]);
  }
  __syncthreads();

  bf16x8 aq[4][2];
  for (int m = 0; m < 4; ++m)
    for (int kk = 0; kk < 2; ++kk) {
      const int row = m*16 + lr;
      aq[m][kk] = *(const bf16x8*)&Qs[row*64 + ((kk*32 + lg*8) ^ ((row & 7) << 3))];
    }

  float rs[4][4] = {};

  // ---- pass 1: row sums of exp(S) (local accumulate, reduce once at end)
  for (int kt = 0; kt < 16; ++kt) {
    const __hip_bfloat16* Kg = Kbase + kt*8192;
    for (int r = 0; r < 4; ++r) {
      const int row = r*32 + wid*8 + (lane >> 3);
      const int sl  = (lane & 7) ^ (row & 7);
      GLOAD16(Kg + row*64 + sl*8, &Ks[r*2048 + wid*512]);
    }
    __syncthreads();
    bf16x8 bk[2][2];
    for (int n = 0; n < 2; ++n)
      for (int kk = 0; kk < 2; ++kk) {
        const int kr = wid*32 + n*16 + lr;
        bk[n][kk] = *(const bf16x8*)&Ks[kr*64 + ((kk*32 + lg*8) ^ ((kr & 7) << 3))];
      }
    f32x4 s[4][2] = {};
    for (int m = 0; m < 4; ++m)
      for (int n = 0; n < 2; ++n)
        for (int kk = 0; kk < 2; ++kk)
          s[m][n] = __builtin_amdgcn_mfma_f32_16x16x32_bf16(aq[m][kk], bk[n][kk], s[m][n], 0, 0, 0);
    for (int m = 0; m < 4; ++m)
      for (int j = 0; j < 4; ++j)
        rs[m][j] += __expf(s[m][0][j]) + __expf(s[m][1][j]);
    __syncthreads();
  }

  // single deferred reduction over the 16 lr lanes, then across waves
  for (int m = 0; m < 4; ++m)
    for (int j = 0; j < 4; ++j) {
      float e = rs[m][j];
      for (int o = 1; o < 16; o <<= 1) e += __shfl_xor(e, o, 64);
      rs[m][j] = e;
    }
  if (lr == 0)
    for (int m = 0; m < 4; ++m)
      for (int j = 0; j < 4; ++j)
        red[wid][m*16 + lg*4 + j] = rs[m][j];
  __syncthreads();
  if (tid < 64)
    invl[tid] = 1.0f / (red[0][tid] + red[1][tid] + red[2][tid] + red[3][tid]);
  __syncthreads();

  float iv[4][4];
  for (int m = 0; m < 4; ++m)
    for (int j = 0; j < 4; ++j)
      iv[m][j] = invl[m*16 + lg*4 + j];

  // ---- pass 2: write attn, accumulate O = P*V
  f32x4 acc_o[4] = {};
  float* attn_row = attn_out + ((long)bh*2048 + qb*64)*2048;

  for (int kt = 0; kt < 16; ++kt) {
    const __hip_bfloat16* Kg = Kbase + kt*8192;
    const __hip_bfloat16* Vg = Vbase + kt*128;
    for (int r = 0; r < 4; ++r) {
      const int row = r*32 + wid*8 + (lane >> 3);
      const int sl  = (lane & 7) ^ (row & 7);
      GLOAD16(Kg + row*64 + sl*8, &Ks[r*2048 + wid*512]);
    }
    for (int r = 0; r < 4; ++r) {
      const int rowd = r*16 + wid*4 + (lane >> 4);
      const int sl   = (lane & 15) ^ (rowd & 15);
      GLOAD16(Vg + (long)rowd*2048 + sl*8, &Vs[r*2048 + wid*512]);
    }
    __syncthreads();

    bf16x8 bk[2][2];
    for (int n = 0; n < 2; ++n)
      for (int kk = 0; kk < 2; ++kk) {
        const int kr = wid*32 + n*16 + lr;
        bk[n][kk] = *(const bf16x8*)&Ks[kr*64 + ((kk*32 + lg*8) ^ ((kr & 7) << 3))];
      }
    f32x4 s[4][2] = {};
    for (int m = 0; m < 4; ++m)
      for (int n = 0; n < 2; ++n)
        for (int kk = 0; kk < 2; ++kk)
          s[m][n] = __builtin_amdgcn_mfma_f32_16x16x32_bf16(aq[m][kk], bk[n][kk], s[m][n], 0, 0, 0);

    for (int m = 0; m < 4; ++m)
      for (int n = 0; n < 2; ++n) {
        const int col = wid*32 + n*16 + lr;
        for (int j = 0; j < 4; ++j) {
          const float p = __expf(s[m][n][j]) * iv[m][j];
          const int row = m*16 + lg*4 + j;
          attn_row[(long)row*2048 + kt*128 + col] = p;
          Ps[row*128 + (col ^ ((row & 15) << 3))] = __float2bfloat16(p);
        }
      }
    __syncthreads();

    bf16x8 vb[4];
    for (int kk2 = 0; kk2 < 4; ++kk2) {
      const int rowd = wid*16 + lr;
      vb[kk2] = *(const bf16x8*)&Vs[rowd*128 + ((kk2*32 + lg*8) ^ ((rowd & 15) << 3))];
    }
    for (int m = 0; m < 4; ++m)
      for (int kk2 = 0; kk2 < 4; ++kk2) {
        const int row = m*16 + lr;
        bf16x8 pa = *(const bf16x8*)&Ps[row*128 + ((kk2*32 + lg*8) ^ ((row & 15) << 3))];
        acc_o[m] = __builtin_amdgcn_mfma_f32_16x16x32_bf16(pa, vb[kk2], acc_o[m], 0, 0, 0);
      }
    __syncthreads();
  }

  const int b_ = bh >> 4, h = bh & 15;
  for (int m = 0; m < 4; ++m)
    for (int j = 0; j < 4; ++j) {
      const long grow = (long)b_*2048 + qb*64 + m*16 + lg*4 + j;
      O[grow*1024 + h*64 + wid*16 + lr] = __float2bfloat16(acc_o[m][j]);
    }
}

// ---------------------------------------------------------------- layernorm
__global__ __launch_bounds__(256)
void ln_kernel(const float* __restrict__ xin, const float* __restrict__ gam,
               const float* __restrict__ bet, float* __restrict__ xout)
{
  const int row = blockIdx.x;
  const int tid = threadIdx.x;
  const float* xr = xin + (long)row*1024;
  float4 v = *(const float4*)(xr + tid*4);
  float s  = v.x + v.y + v.z + v.w;
  float ss = v.x*v.x + v.y*v.y + v.z*v.z + v.w*v.w;
  for (int o = 1; o < 64; o <<= 1) {
    s  += __shfl_xor(s, o, 64);
    ss += __shfl_xor(ss, o, 64);
  }
  __shared__ float rsh[4], rssh[4];
  const int wid = tid >> 6, lane = tid & 63;
  if (lane == 0) { rsh[wid] = s; rssh[wid] = ss; }
  __syncthreads();
  s  = rsh[0] + rsh[1] + rsh[2] + rsh[3];
  ss = rssh[0] + rssh[1] + rssh[2] + rssh[3];
  const float mean = s * (1.0f/1024.0f);
  const float var  = ss * (1.0f/1024.0f) - mean*mean;
  const float rstd = rsqrtf(var + 1e-5f);
  float4 g4 = *(const float4*)(gam + tid*4);
  float4 b4 = *(const float4*)(bet + tid*4);
  float4 o4;
  o4.x = (v.x - mean)*rstd*g4.x + b4.x;
  o4.y = (v.y - mean)*rstd*g4.y + b4.y;
  o4.z = (v.z - mean)*rstd*g4.z + b4.z;
  o4.w = (v.w - mean)*rstd*g4.w + b4.w;
  *(float4*)(xout + (long)row*1024 + tid*4) = o4;
}

// ---------------------------------------------------------------- launch
extern "C" void kernel_launch(void* const* d_in, const int* in_sizes, int n_in,
                              void* d_out, int out_size, void* d_ws, size_t ws_size,
                              hipStream_t stream)
{
  (void)in_sizes; (void)n_in; (void)out_size; (void)ws_size;
  const float* q    = (const float*)d_in[0];
  const float* k    = (const float*)d_in[1];
  const float* v    = (const float*)d_in[2];
  const float* w_q  = (const float*)d_in[3];
  const float* w_k  = (const float*)d_in[4];
  const float* w_v  = (const float*)d_in[5];
  const float* w_fc = (const float*)d_in[6];
  const float* b_fc = (const float*)d_in[7];
  const float* ln_g = (const float*)d_in[8];
  const float* ln_b = (const float*)d_in[9];

  const long MB = 1024*1024;
  char* ws = (char*)d_ws;
  __hip_bfloat16* q_bf  = (__hip_bfloat16*)(ws);
  __hip_bfloat16* k_bf  = (__hip_bfloat16*)(ws +  8*MB);
  __hip_bfloat16* v_bf  = (__hip_bfloat16*)(ws + 16*MB);
  __hip_bfloat16* wq_t  = (__hip_bfloat16*)(ws + 24*MB);
  __hip_bfloat16* wk_t  = (__hip_bfloat16*)(ws + 26*MB);
  __hip_bfloat16* wv_t  = (__hip_bfloat16*)(ws + 28*MB);
  __hip_bfloat16* wfc_t = (__hip_bfloat16*)(ws + 30*MB);
  __hip_bfloat16* QKVh  = (__hip_bfloat16*)(ws + 32*MB);  // Qh|Kh|Vh contiguous, 8MB each
  __hip_bfloat16* Qh    = QKVh;
  __hip_bfloat16* Kh    = QKVh + 4194304L;
  __hip_bfloat16* Vh    = QKVh + 8388608L;
  __hip_bfloat16* Vht   = (__hip_bfloat16*)(ws + 56*MB);
  __hip_bfloat16* Obuf  = (__hip_bfloat16*)(ws + 64*MB);
  float*          xbuf  = (float*)(ws + 72*MB);

  float* x_out    = (float*)d_out;
  float* attn_out = x_out + 4194304L;

  const int NQ = 4096*1024;
  cvt_kernel<<<dim3(NQ/2048, 3), 256, 0, stream>>>(q, k, v, q_bf, k_bf, v_bf, NQ);

  wtrans_kernel<<<dim3(16, 16, 4), 256, 0, stream>>>(w_q, w_k, w_v, w_fc,
                                                     wq_t, wk_t, wv_t, wfc_t);

  gemm_bt<0><<<dim3(8, 32, 3), 256, 0, stream>>>(q_bf, k_bf, v_bf, wq_t, wk_t, wv_t,
                                                 QKVh, nullptr, nullptr, 4096, 1024, 1024);

  vtrans_kernel<<<dim3(32, 32), 256, 0, stream>>>(Vh, Vht);

  attn_kernel<<<dim3(32, 32), 256, 0, stream>>>(Qh, Kh, Vht, attn_out, Obuf);

  gemm_bt<2><<<dim3(8, 32), 256, 0, stream>>>(Obuf, nullptr, nullptr, wfc_t, nullptr, nullptr,
                                              xbuf, b_fc, q, 4096, 1024, 1024);

  ln_kernel<<<4096, 256, 0, stream>>>(xbuf, ln_g, ln_b, x_out);
}